// Round 2
// baseline (317.526 us; speedup 1.0000x reference)
//
#include <hip/hip_runtime.h>
#include <hip/hip_bf16.h>

#define D_FEAT 768

typedef __bf16 bf16x8 __attribute__((ext_vector_type(8)));
typedef float floatx4 __attribute__((ext_vector_type(4)));
typedef unsigned short ushort8 __attribute__((ext_vector_type(8)));

__device__ __forceinline__ unsigned short f2bf(float f) {
    unsigned int x = __builtin_bit_cast(unsigned int, f);
    unsigned int lsb = (x >> 16) & 1u;
    x += 0x7fffu + lsb;            // round-to-nearest-even
    return (unsigned short)(x >> 16);
}

// -------- W convert+transpose: Wt[n][k] = bf16(W[k][n]) (768x768) ------------
__global__ __launch_bounds__(256) void transpose_kernel(
    const float* __restrict__ W, unsigned short* __restrict__ Wt)
{
    __shared__ float tile[32][33];
    int x0 = blockIdx.x * 32, y0 = blockIdx.y * 32;
    int tx = threadIdx.x & 31, ty = threadIdx.x >> 5;   // 32 x 8
    for (int r = ty; r < 32; r += 8)
        tile[r][tx] = W[(size_t)(y0 + r) * D_FEAT + x0 + tx];
    __syncthreads();
    for (int r = ty; r < 32; r += 8)
        Wt[(size_t)(x0 + r) * D_FEAT + y0 + tx] = f2bf(tile[tx][r]);
}

// -------- GEMM: C[M,768] = A[M,768] @ Bt[768,768]^T  (A f32 or bf16) ---------
// Block tile 64(m) x 128(n), BK=32. 4 waves in 2x2, each wave 32x64 (2x4 frags).
template <bool A_IS_F32>
__global__ __launch_bounds__(256) void gemm_kernel(
    const void* __restrict__ Av,             // [M,768] f32 or bf16 row-major
    const unsigned short* __restrict__ Bt,   // [768,768] bf16, Bt[n][k]
    float* __restrict__ C, int M)
{
    constexpr int LDP = 48;                  // padded LDS row (bf16 elems)
    __shared__ __align__(16) unsigned short sA[64 * LDP];
    __shared__ __align__(16) unsigned short sB[128 * LDP];

    const int tid = threadIdx.x;
    const int m0 = blockIdx.x * 64;
    const int n0 = blockIdx.y * 128;
    const int lane = tid & 63, wave = tid >> 6;
    const int wm = wave >> 1, wn = wave & 1;
    const int l15 = lane & 15, quad = lane >> 4;

    const int ar = tid >> 2;                 // 0..63
    const int ac = (tid & 3) * 8;            // 0,8,16,24
    const int br = tid >> 1;                 // 0..127
    const int bc = (tid & 1) * 16;           // 0 or 16

    int arow = m0 + ar; if (arow >= M) arow = M - 1;   // clamp (stores guarded)

    floatx4 acc[2][4];
    #pragma unroll
    for (int i = 0; i < 2; ++i)
        #pragma unroll
        for (int j = 0; j < 4; ++j)
            acc[i][j] = (floatx4){0.f, 0.f, 0.f, 0.f};

    for (int kt = 0; kt < 768; kt += 32) {
        __syncthreads();
        if constexpr (A_IS_F32) {
            const float* Af = (const float*)Av;
            float4 p0 = *(const float4*)&Af[(size_t)arow * 768 + kt + ac];
            float4 p1 = *(const float4*)&Af[(size_t)arow * 768 + kt + ac + 4];
            ushort8 v;
            v[0] = f2bf(p0.x); v[1] = f2bf(p0.y); v[2] = f2bf(p0.z); v[3] = f2bf(p0.w);
            v[4] = f2bf(p1.x); v[5] = f2bf(p1.y); v[6] = f2bf(p1.z); v[7] = f2bf(p1.w);
            *(ushort8*)&sA[ar * LDP + ac] = v;
        } else {
            const unsigned short* Ab = (const unsigned short*)Av;
            *(int4*)&sA[ar * LDP + ac] = *(const int4*)&Ab[(size_t)arow * 768 + kt + ac];
        }
        *(int4*)&sB[br * LDP + bc]     = *(const int4*)&Bt[(size_t)(n0 + br) * 768 + kt + bc];
        *(int4*)&sB[br * LDP + bc + 8] = *(const int4*)&Bt[(size_t)(n0 + br) * 768 + kt + bc + 8];
        __syncthreads();

        bf16x8 af[2], bfrag[4];
        #pragma unroll
        for (int i = 0; i < 2; ++i)
            af[i] = *(const bf16x8*)&sA[(wm * 32 + i * 16 + l15) * LDP + quad * 8];
        #pragma unroll
        for (int j = 0; j < 4; ++j)
            bfrag[j] = *(const bf16x8*)&sB[(wn * 64 + j * 16 + l15) * LDP + quad * 8];
        #pragma unroll
        for (int i = 0; i < 2; ++i)
            #pragma unroll
            for (int j = 0; j < 4; ++j)
                acc[i][j] = __builtin_amdgcn_mfma_f32_16x16x32_bf16(af[i], bfrag[j], acc[i][j], 0, 0, 0);
    }

    #pragma unroll
    for (int i = 0; i < 2; ++i)
        #pragma unroll
        for (int j = 0; j < 4; ++j)
            #pragma unroll
            for (int r = 0; r < 4; ++r) {
                int m = m0 + wm * 32 + i * 16 + quad * 4 + r;   // row = quad*4+reg
                int n = n0 + wn * 64 + j * 16 + l15;            // col = lane&15
                if (m < M) C[(size_t)m * 768 + n] = acc[i][j][r];
            }
}

// -------- per-node attention dots: es/ed = h . a_src / a_dst -----------------
__global__ __launch_bounds__(256) void dots_kernel(
    const float* __restrict__ h, const float* __restrict__ asrc,
    const float* __restrict__ adst, float* __restrict__ es,
    float* __restrict__ ed)
{
    __shared__ float r1[256], r2[256];
    int n = blockIdx.x, t = threadIdx.x;
    const float* hr = h + (size_t)n * 768;
    float s1 = 0.f, s2 = 0.f;
    #pragma unroll
    for (int k = 0; k < 3; ++k) {
        int d = t + k * 256;
        float hv = hr[d];
        s1 += hv * asrc[d];
        s2 += hv * adst[d];
    }
    r1[t] = s1; r2[t] = s2; __syncthreads();
    for (int s = 128; s > 0; s >>= 1) {
        if (t < s) { r1[t] += r1[t + s]; r2[t] += r2[t + s]; }
        __syncthreads();
    }
    if (t == 0) { es[n] = r1[0]; ed[n] = r2[0]; }
}

// -------- CSR build ----------------------------------------------------------
__global__ void init_deg_kernel(int* deg, int n) {
    int i = blockIdx.x * blockDim.x + threadIdx.x;
    if (i < n) deg[i] = 1;                    // self loop pre-counted
}
__global__ void count_kernel(const int* __restrict__ dst, int* __restrict__ deg, int e) {
    int i = blockIdx.x * blockDim.x + threadIdx.x;
    if (i < e) atomicAdd(&deg[dst[i]], 1);
}
__global__ __launch_bounds__(1024) void scan_kernel(
    const int* __restrict__ deg, int* __restrict__ row_ptr,
    int* __restrict__ cursor, int n)
{
    __shared__ int part[1024];
    int t = threadIdx.x;
    int per = (n + 1023) / 1024;
    int base = t * per;
    int s = 0;
    for (int i = 0; i < per; ++i) { int idx = base + i; if (idx < n) s += deg[idx]; }
    part[t] = s; __syncthreads();
    for (int off = 1; off < 1024; off <<= 1) {
        int v = (t >= off) ? part[t - off] : 0;
        __syncthreads();
        part[t] += v;
        __syncthreads();
    }
    int run = (t == 0) ? 0 : part[t - 1];
    for (int i = 0; i < per; ++i) {
        int idx = base + i;
        if (idx < n) { row_ptr[idx] = run; cursor[idx] = run; run += deg[idx]; }
    }
    if (t == 1023) row_ptr[n] = part[1023];
}
__global__ void fill_kernel(const int* __restrict__ src, const int* __restrict__ dst,
                            int* __restrict__ cursor, int* __restrict__ col_src,
                            int e, int n)
{
    int i = blockIdx.x * blockDim.x + threadIdx.x;
    if (i >= e + n) return;
    int s, d;
    if (i < e) { s = src[i]; d = dst[i]; } else { s = i - e; d = s; }
    int pos = atomicAdd(&cursor[d], 1);
    col_src[pos] = s;
}

// -------- per-dst-node segment softmax + weighted aggregation ----------------
// Layer 1 (out_bf != null): writes relu(out) as bf16 for next GEMM.
// Layer 2 (out_f  != null): writes f32 to d_out.
__global__ __launch_bounds__(256) void agg_kernel(
    const float* __restrict__ h, const float* __restrict__ es,
    const float* __restrict__ ed, const int* __restrict__ row_ptr,
    const int* __restrict__ col_src, const float* __restrict__ bias,
    unsigned short* __restrict__ out_bf, float* __restrict__ out_f)
{
    __shared__ float red[256];
    int n = blockIdx.x, t = threadIdx.x;
    int beg = row_ptr[n], end = row_ptr[n + 1];
    float edn = ed[n];

    // pass 1: segment max of leaky_relu(es[src]+ed[dst])
    float lm = -3.4e38f;
    for (int i = beg + t; i < end; i += 256) {
        float v = es[col_src[i]] + edn;
        v = v > 0.f ? v : 0.2f * v;
        lm = fmaxf(lm, v);
    }
    red[t] = lm; __syncthreads();
    for (int s = 128; s > 0; s >>= 1) { if (t < s) red[t] = fmaxf(red[t], red[t + s]); __syncthreads(); }
    float mx = red[0]; __syncthreads();

    // pass 2: sum of exp(e - mx)
    float ls = 0.f;
    for (int i = beg + t; i < end; i += 256) {
        float v = es[col_src[i]] + edn;
        v = v > 0.f ? v : 0.2f * v;
        ls += __expf(v - mx);
    }
    red[t] = ls; __syncthreads();
    for (int s = 128; s > 0; s >>= 1) { if (t < s) red[t] += red[t + s]; __syncthreads(); }
    float rz = 1.f / red[0];

    // pass 3: out[n,:] = sum_e alpha_e * h[src_e,:]  (each thread owns 3 dims)
    float a0 = 0.f, a1 = 0.f, a2 = 0.f;
    for (int i = beg; i < end; ++i) {
        int sidx = col_src[i];                   // uniform per iteration -> cache broadcast
        float v = es[sidx] + edn;
        v = v > 0.f ? v : 0.2f * v;
        float w = __expf(v - mx) * rz;
        const float* hr = h + (size_t)sidx * 768;
        a0 += w * hr[t];
        a1 += w * hr[t + 256];
        a2 += w * hr[t + 512];
    }
    float o0 = a0 + bias[t];
    float o1 = a1 + bias[t + 256];
    float o2 = a2 + bias[t + 512];
    size_t base = (size_t)n * 768;
    if (out_bf) {
        o0 = fmaxf(o0, 0.f); o1 = fmaxf(o1, 0.f); o2 = fmaxf(o2, 0.f);  // relu
        out_bf[base + t]       = f2bf(o0);
        out_bf[base + t + 256] = f2bf(o1);
        out_bf[base + t + 512] = f2bf(o2);
    } else {
        out_f[base + t]       = o0;
        out_f[base + t + 256] = o1;
        out_f[base + t + 512] = o2;
    }
}

// -----------------------------------------------------------------------------
extern "C" void kernel_launch(void* const* d_in, const int* in_sizes, int n_in,
                              void* d_out, int out_size, void* d_ws, size_t ws_size,
                              hipStream_t stream)
{
    const float* x   = (const float*)d_in[0];
    const int*   ei  = (const int*)d_in[1];
    const float* W1  = (const float*)d_in[2];
    const float* as1 = (const float*)d_in[3];
    const float* ad1 = (const float*)d_in[4];
    const float* b1  = (const float*)d_in[5];
    const float* W2  = (const float*)d_in[6];
    const float* as2 = (const float*)d_in[7];
    const float* ad2 = (const float*)d_in[8];
    const float* b2  = (const float*)d_in[9];

    const int N = in_sizes[0] / D_FEAT;
    const int E = in_sizes[1] / 2;
    const int* src = ei;
    const int* dst = ei + E;

    char* ws = (char*)d_ws;
    size_t off = 0;
    auto alloc = [&](size_t bytes) -> void* {
        void* p = ws + off;
        off += (bytes + 255) & ~(size_t)255;
        return p;
    };
    unsigned short* Wt1  = (unsigned short*)alloc((size_t)768 * 768 * 2);
    unsigned short* Wt2  = (unsigned short*)alloc((size_t)768 * 768 * 2);
    float*          h    = (float*)alloc((size_t)N * 768 * 4);
    unsigned short* x2b  = (unsigned short*)alloc((size_t)N * 768 * 2);
    float*          es   = (float*)alloc((size_t)N * 4);
    float*          ed   = (float*)alloc((size_t)N * 4);
    int*            deg  = (int*)alloc((size_t)N * 4);
    int*            cur  = (int*)alloc((size_t)N * 4);
    int*            rowp = (int*)alloc((size_t)(N + 1) * 4);
    int*            col  = (int*)alloc((size_t)(E + N) * 4);

    dim3 tgrid(D_FEAT / 32, D_FEAT / 32);
    transpose_kernel<<<tgrid, 256, 0, stream>>>(W1, Wt1);
    transpose_kernel<<<tgrid, 256, 0, stream>>>(W2, Wt2);

    init_deg_kernel<<<(N + 255) / 256, 256, 0, stream>>>(deg, N);
    count_kernel<<<(E + 255) / 256, 256, 0, stream>>>(dst, deg, E);
    scan_kernel<<<1, 1024, 0, stream>>>(deg, rowp, cur, N);
    fill_kernel<<<(E + N + 255) / 256, 256, 0, stream>>>(src, dst, cur, col, E, N);

    dim3 ggrid((N + 63) / 64, D_FEAT / 128);
    // layer 1
    gemm_kernel<true><<<ggrid, 256, 0, stream>>>(x, Wt1, h, N);
    dots_kernel<<<N, 256, 0, stream>>>(h, as1, ad1, es, ed);
    agg_kernel<<<N, 256, 0, stream>>>(h, es, ed, rowp, col, b1, x2b, nullptr);
    // layer 2
    gemm_kernel<false><<<ggrid, 256, 0, stream>>>(x2b, Wt2, h, N);
    dots_kernel<<<N, 256, 0, stream>>>(h, as2, ad2, es, ed);
    agg_kernel<<<N, 256, 0, stream>>>(h, es, ed, rowp, col, b2, nullptr, (float*)d_out);
}

// Round 3
// 282.671 us; speedup vs baseline: 1.1233x; 1.1233x over previous
//
#include <hip/hip_runtime.h>
#include <hip/hip_bf16.h>

#define D_FEAT 768
#define AGG_CAP 3072   // LDS-cached edges per node (degree ~11 avg; fallback path covers overflow)

typedef __bf16 bf16x8 __attribute__((ext_vector_type(8)));
typedef float floatx4 __attribute__((ext_vector_type(4)));

__device__ __forceinline__ float bf2f(unsigned short u) {
    unsigned int x = ((unsigned int)u) << 16;
    return __builtin_bit_cast(float, x);
}
__device__ __forceinline__ unsigned short f2bf(float f) {
    unsigned int x = __builtin_bit_cast(unsigned int, f);
    unsigned int lsb = (x >> 16) & 1u;
    x += 0x7fffu + lsb;            // round-to-nearest-even
    return (unsigned short)(x >> 16);
}
__device__ __forceinline__ void async_ld16(const void* g, void* l) {
    __builtin_amdgcn_global_load_lds(
        (__attribute__((address_space(1))) void*)(g),
        (__attribute__((address_space(3))) void*)(l), 16, 0, 0);
}

// -------- x f32 -> bf16 pre-convert ------------------------------------------
__global__ __launch_bounds__(256) void conv_kernel(
    const float* __restrict__ x, unsigned short* __restrict__ xb, int n4)
{
    int i = blockIdx.x * 256 + threadIdx.x;
    if (i < n4) {
        float4 v = ((const float4*)x)[i];
        ushort4 o;
        o.x = f2bf(v.x); o.y = f2bf(v.y); o.z = f2bf(v.z); o.w = f2bf(v.w);
        ((ushort4*)xb)[i] = o;
    }
}

// -------- W convert+transpose: Wt[n][k] = bf16(W[k][n]) (768x768) ------------
__global__ __launch_bounds__(256) void transpose_kernel(
    const float* __restrict__ W, unsigned short* __restrict__ Wt)
{
    __shared__ float tile[32][33];
    int x0 = blockIdx.x * 32, y0 = blockIdx.y * 32;
    int tx = threadIdx.x & 31, ty = threadIdx.x >> 5;   // 32 x 8
    for (int r = ty; r < 32; r += 8)
        tile[r][tx] = W[(size_t)(y0 + r) * D_FEAT + x0 + tx];
    __syncthreads();
    for (int r = ty; r < 32; r += 8)
        Wt[(size_t)(x0 + r) * D_FEAT + y0 + tx] = f2bf(tile[tx][r]);
}

// -------- GEMM: C[M,768] = A[M,768] @ Bt^T, bf16 in -> bf16 out --------------
// 64(m) x 128(n) tile, BK=32, global_load_lds width-16 staging, unpadded LDS.
__global__ __launch_bounds__(256) void gemm_kernel(
    const unsigned short* __restrict__ A,    // [M,768] bf16 row-major
    const unsigned short* __restrict__ Bt,   // [768,768] bf16, Bt[n][k]
    unsigned short* __restrict__ C,          // [M,768] bf16
    int M)
{
    __shared__ __align__(16) unsigned short sA[64 * 32];    // 4 KB
    __shared__ __align__(16) unsigned short sB[128 * 32];   // 8 KB

    const int tid = threadIdx.x;
    const int lane = tid & 63, wave = tid >> 6;
    const int m0 = blockIdx.x * 64;
    const int n0 = blockIdx.y * 128;
    const int wm = wave >> 1, wn = wave & 1;
    const int l15 = lane & 15, quad = lane >> 4;

    // staging: each wave fills 1KB of sA + 2KB of sB per K-tile (lane i -> base+16*i)
    int arow = m0 + wave * 16 + (lane >> 2); if (arow >= M) arow = M - 1;
    const unsigned short* aptr  = A  + (size_t)arow * 768 + (lane & 3) * 8;
    int brow = n0 + wave * 32 + (lane >> 2);
    const unsigned short* bptr0 = Bt + (size_t)brow * 768 + (lane & 3) * 8;
    const unsigned short* bptr1 = bptr0 + (size_t)16 * 768;
    unsigned short* aldst  = &sA[wave * 512];
    unsigned short* bldst0 = &sB[wave * 1024];
    unsigned short* bldst1 = &sB[wave * 1024 + 512];

    floatx4 acc[2][4];
    #pragma unroll
    for (int i = 0; i < 2; ++i)
        #pragma unroll
        for (int j = 0; j < 4; ++j)
            acc[i][j] = (floatx4){0.f, 0.f, 0.f, 0.f};

    for (int kt = 0; kt < 768; kt += 32) {
        __syncthreads();
        async_ld16(aptr  + kt, aldst);
        async_ld16(bptr0 + kt, bldst0);
        async_ld16(bptr1 + kt, bldst1);
        __syncthreads();

        bf16x8 af[2], bfr[4];
        #pragma unroll
        for (int i = 0; i < 2; ++i)
            af[i] = *(const bf16x8*)&sA[(wm * 32 + i * 16 + l15) * 32 + quad * 8];
        #pragma unroll
        for (int j = 0; j < 4; ++j)
            bfr[j] = *(const bf16x8*)&sB[(wn * 64 + j * 16 + l15) * 32 + quad * 8];
        #pragma unroll
        for (int i = 0; i < 2; ++i)
            #pragma unroll
            for (int j = 0; j < 4; ++j)
                acc[i][j] = __builtin_amdgcn_mfma_f32_16x16x32_bf16(af[i], bfr[j], acc[i][j], 0, 0, 0);
    }

    #pragma unroll
    for (int i = 0; i < 2; ++i)
        #pragma unroll
        for (int j = 0; j < 4; ++j)
            #pragma unroll
            for (int r = 0; r < 4; ++r) {
                int m = m0 + wm * 32 + i * 16 + quad * 4 + r;   // row = quad*4+reg
                int n = n0 + wn * 64 + j * 16 + l15;            // col = lane&15
                if (m < M) C[(size_t)m * 768 + n] = f2bf(acc[i][j][r]);
            }
}

// -------- per-node attention dots: es/ed = h . a_src / a_dst (h bf16) --------
__global__ __launch_bounds__(256) void dots_kernel(
    const unsigned short* __restrict__ h, const float* __restrict__ asrc,
    const float* __restrict__ adst, float* __restrict__ es,
    float* __restrict__ ed, int N)
{
    int wid = threadIdx.x >> 6, lane = threadIdx.x & 63;
    int n = blockIdx.x * 4 + wid;
    if (n >= N) return;
    const unsigned short* hr = h + (size_t)n * 768 + lane * 12;
    float s1 = 0.f, s2 = 0.f;
    #pragma unroll
    for (int c = 0; c < 3; ++c) {
        ushort4 v = *(const ushort4*)(hr + c * 4);
        int d = lane * 12 + c * 4;
        float f0 = bf2f(v.x), f1 = bf2f(v.y), f2v = bf2f(v.z), f3 = bf2f(v.w);
        s1 += f0 * asrc[d] + f1 * asrc[d + 1] + f2v * asrc[d + 2] + f3 * asrc[d + 3];
        s2 += f0 * adst[d] + f1 * adst[d + 1] + f2v * adst[d + 2] + f3 * adst[d + 3];
    }
    #pragma unroll
    for (int m = 32; m >= 1; m >>= 1) {
        s1 += __shfl_xor(s1, m, 64);
        s2 += __shfl_xor(s2, m, 64);
    }
    if (lane == 0) { es[n] = s1; ed[n] = s2; }
}

// -------- CSR build ----------------------------------------------------------
__global__ void init_deg_kernel(int* deg, int n) {
    int i = blockIdx.x * blockDim.x + threadIdx.x;
    if (i < n) deg[i] = 1;                    // self loop pre-counted
}
__global__ void count_kernel(const int* __restrict__ dst, int* __restrict__ deg, int e) {
    int i = blockIdx.x * blockDim.x + threadIdx.x;
    if (i < e) atomicAdd(&deg[dst[i]], 1);
}
__global__ __launch_bounds__(1024) void scan_kernel(
    const int* __restrict__ deg, int* __restrict__ row_ptr,
    int* __restrict__ cursor, int n)
{
    __shared__ int part[1024];
    int t = threadIdx.x;
    int per = (n + 1023) / 1024;
    int base = t * per;
    int s = 0;
    for (int i = 0; i < per; ++i) { int idx = base + i; if (idx < n) s += deg[idx]; }
    part[t] = s; __syncthreads();
    for (int off = 1; off < 1024; off <<= 1) {
        int v = (t >= off) ? part[t - off] : 0;
        __syncthreads();
        part[t] += v;
        __syncthreads();
    }
    int run = (t == 0) ? 0 : part[t - 1];
    for (int i = 0; i < per; ++i) {
        int idx = base + i;
        if (idx < n) { row_ptr[idx] = run; cursor[idx] = run; run += deg[idx]; }
    }
    if (t == 1023) row_ptr[n] = part[1023];
}
__global__ void fill_kernel(const int* __restrict__ src, const int* __restrict__ dst,
                            int* __restrict__ cursor, int* __restrict__ col_src,
                            int e, int n)
{
    int i = blockIdx.x * blockDim.x + threadIdx.x;
    if (i >= e + n) return;
    int s, d;
    if (i < e) { s = src[i]; d = dst[i]; } else { s = i - e; d = s; }
    int pos = atomicAdd(&cursor[d], 1);
    col_src[pos] = s;
}

// -------- per-dst segment softmax + weighted aggregation (h bf16) ------------
__global__ __launch_bounds__(256) void agg_kernel(
    const unsigned short* __restrict__ h, const float* __restrict__ es,
    const float* __restrict__ ed, const int* __restrict__ row_ptr,
    const int* __restrict__ col_src, const float* __restrict__ bias,
    unsigned short* __restrict__ out_bf, float* __restrict__ out_f)
{
    __shared__ float wsh[AGG_CAP];
    __shared__ int   ssh[AGG_CAP];
    __shared__ float red[256];
    int n = blockIdx.x, t = threadIdx.x;
    int beg = row_ptr[n], end = row_ptr[n + 1], deg = end - beg;
    float edn = ed[n];

    // phase 1: fetch edges, compute leaky-relu logits, cache in LDS, find max
    float lm = -3.4e38f;
    for (int i = t; i < deg; i += 256) {
        int s = col_src[beg + i];
        float v = es[s] + edn;
        v = v > 0.f ? v : 0.2f * v;
        if (i < AGG_CAP) { ssh[i] = s; wsh[i] = v; }
        lm = fmaxf(lm, v);
    }
    red[t] = lm; __syncthreads();
    for (int s = 128; s > 0; s >>= 1) { if (t < s) red[t] = fmaxf(red[t], red[t + s]); __syncthreads(); }
    float mx = red[0]; __syncthreads();

    // phase 2: exponentiate (in place) + sum
    float ls = 0.f;
    for (int i = t; i < deg; i += 256) {
        float v;
        if (i < AGG_CAP) v = wsh[i];
        else { float u = es[col_src[beg + i]] + edn; v = u > 0.f ? u : 0.2f * u; }
        float w = __expf(v - mx);
        if (i < AGG_CAP) wsh[i] = w;
        ls += w;
    }
    red[t] = ls; __syncthreads();
    for (int s = 128; s > 0; s >>= 1) { if (t < s) red[t] += red[t + s]; __syncthreads(); }
    float rz = 1.f / red[0];

    // phase 3: threads 0..191 each own 4 contiguous dims; gather-weighted sum
    if (t < 192) {
        float a0 = 0.f, a1 = 0.f, a2 = 0.f, a3 = 0.f;
        const unsigned short* hb = h + t * 4;
        for (int i = 0; i < deg; ++i) {
            int s; float w;
            if (i < AGG_CAP) { s = ssh[i]; w = wsh[i]; }
            else {
                s = col_src[beg + i];
                float u = es[s] + edn; u = u > 0.f ? u : 0.2f * u;
                w = __expf(u - mx);
            }
            ushort4 hv = *(const ushort4*)(hb + (size_t)s * 768);
            a0 += w * bf2f(hv.x); a1 += w * bf2f(hv.y);
            a2 += w * bf2f(hv.z); a3 += w * bf2f(hv.w);
        }
        float4 bv = *(const float4*)&bias[t * 4];
        float o0 = a0 * rz + bv.x, o1 = a1 * rz + bv.y;
        float o2 = a2 * rz + bv.z, o3 = a3 * rz + bv.w;
        size_t base = (size_t)n * 768 + t * 4;
        if (out_bf) {   // layer 1: relu + bf16 for next GEMM
            o0 = fmaxf(o0, 0.f); o1 = fmaxf(o1, 0.f);
            o2 = fmaxf(o2, 0.f); o3 = fmaxf(o3, 0.f);
            ushort4 o; o.x = f2bf(o0); o.y = f2bf(o1); o.z = f2bf(o2); o.w = f2bf(o3);
            *(ushort4*)&out_bf[base] = o;
        } else {        // layer 2: f32 final output
            float4 o; o.x = o0; o.y = o1; o.z = o2; o.w = o3;
            *(float4*)&out_f[base] = o;
        }
    }
}

// -----------------------------------------------------------------------------
extern "C" void kernel_launch(void* const* d_in, const int* in_sizes, int n_in,
                              void* d_out, int out_size, void* d_ws, size_t ws_size,
                              hipStream_t stream)
{
    const float* x   = (const float*)d_in[0];
    const int*   ei  = (const int*)d_in[1];
    const float* W1  = (const float*)d_in[2];
    const float* as1 = (const float*)d_in[3];
    const float* ad1 = (const float*)d_in[4];
    const float* b1  = (const float*)d_in[5];
    const float* W2  = (const float*)d_in[6];
    const float* as2 = (const float*)d_in[7];
    const float* ad2 = (const float*)d_in[8];
    const float* b2  = (const float*)d_in[9];

    const int N = in_sizes[0] / D_FEAT;
    const int E = in_sizes[1] / 2;
    const int* src = ei;
    const int* dst = ei + E;

    char* ws = (char*)d_ws;
    size_t off = 0;
    auto alloc = [&](size_t bytes) -> void* {
        void* p = ws + off;
        off += (bytes + 255) & ~(size_t)255;
        return p;
    };
    unsigned short* Wt1  = (unsigned short*)alloc((size_t)768 * 768 * 2);
    unsigned short* Wt2  = (unsigned short*)alloc((size_t)768 * 768 * 2);
    unsigned short* xb   = (unsigned short*)alloc((size_t)N * 768 * 2);
    unsigned short* h    = (unsigned short*)alloc((size_t)N * 768 * 2);   // bf16 activations
    unsigned short* x2b  = (unsigned short*)alloc((size_t)N * 768 * 2);
    float*          es   = (float*)alloc((size_t)N * 4);
    float*          ed   = (float*)alloc((size_t)N * 4);
    int*            deg  = (int*)alloc((size_t)N * 4);
    int*            cur  = (int*)alloc((size_t)N * 4);
    int*            rowp = (int*)alloc((size_t)(N + 1) * 4);
    int*            col  = (int*)alloc((size_t)(E + N) * 4);

    // prep: x -> bf16, W -> bf16 transposed, CSR by dst
    int n4 = N * 768 / 4;
    conv_kernel<<<(n4 + 255) / 256, 256, 0, stream>>>(x, xb, n4);
    dim3 tgrid(D_FEAT / 32, D_FEAT / 32);
    transpose_kernel<<<tgrid, 256, 0, stream>>>(W1, Wt1);
    transpose_kernel<<<tgrid, 256, 0, stream>>>(W2, Wt2);
    init_deg_kernel<<<(N + 255) / 256, 256, 0, stream>>>(deg, N);
    count_kernel<<<(E + 255) / 256, 256, 0, stream>>>(dst, deg, E);
    scan_kernel<<<1, 1024, 0, stream>>>(deg, rowp, cur, N);
    fill_kernel<<<(E + N + 255) / 256, 256, 0, stream>>>(src, dst, cur, col, E, N);

    dim3 ggrid((N + 63) / 64, D_FEAT / 128);
    // layer 1
    gemm_kernel<<<ggrid, 256, 0, stream>>>(xb, Wt1, h, N);
    dots_kernel<<<(N + 3) / 4, 256, 0, stream>>>(h, as1, ad1, es, ed, N);
    agg_kernel<<<N, 256, 0, stream>>>(h, es, ed, rowp, col, b1, x2b, nullptr);
    // layer 2
    gemm_kernel<<<ggrid, 256, 0, stream>>>(x2b, Wt2, h, N);
    dots_kernel<<<(N + 3) / 4, 256, 0, stream>>>(h, as2, ad2, es, ed, N);
    agg_kernel<<<N, 256, 0, stream>>>(h, es, ed, rowp, col, b2, nullptr, (float*)d_out);
}

// Round 4
// 252.312 us; speedup vs baseline: 1.2585x; 1.1203x over previous
//
#include <hip/hip_runtime.h>
#include <hip/hip_bf16.h>

#define D_FEAT 768

typedef __bf16 bf16x8 __attribute__((ext_vector_type(8)));
typedef float floatx4 __attribute__((ext_vector_type(4)));

__device__ __forceinline__ float bf2f(unsigned short u) {
    unsigned int x = ((unsigned int)u) << 16;
    return __builtin_bit_cast(float, x);
}
__device__ __forceinline__ unsigned short f2bf(float f) {
    unsigned int x = __builtin_bit_cast(unsigned int, f);
    unsigned int lsb = (x >> 16) & 1u;
    x += 0x7fffu + lsb;            // round-to-nearest-even
    return (unsigned short)(x >> 16);
}
__device__ __forceinline__ void async_ld16(const void* g, void* l) {
    __builtin_amdgcn_global_load_lds(
        (__attribute__((address_space(1))) void*)(g),
        (__attribute__((address_space(3))) void*)(l), 16, 0, 0);
}

// -------- x f32 -> bf16 pre-convert ------------------------------------------
__global__ __launch_bounds__(256) void conv_kernel(
    const float* __restrict__ x, unsigned short* __restrict__ xb, int n4)
{
    int i = blockIdx.x * 256 + threadIdx.x;
    if (i < n4) {
        float4 v = ((const float4*)x)[i];
        ushort4 o;
        o.x = f2bf(v.x); o.y = f2bf(v.y); o.z = f2bf(v.z); o.w = f2bf(v.w);
        ((ushort4*)xb)[i] = o;
    }
}

// -------- W convert+transpose: Wt[n][k] = bf16(W[k][n]) (768x768) ------------
__global__ __launch_bounds__(256) void transpose_kernel(
    const float* __restrict__ W, unsigned short* __restrict__ Wt)
{
    __shared__ float tile[32][33];
    int x0 = blockIdx.x * 32, y0 = blockIdx.y * 32;
    int tx = threadIdx.x & 31, ty = threadIdx.x >> 5;   // 32 x 8
    for (int r = ty; r < 32; r += 8)
        tile[r][tx] = W[(size_t)(y0 + r) * D_FEAT + x0 + tx];
    __syncthreads();
    for (int r = ty; r < 32; r += 8)
        Wt[(size_t)(x0 + r) * D_FEAT + y0 + tx] = f2bf(tile[tx][r]);
}

// -------- GEMM 128x128 + fused attention dots --------------------------------
// C[M,768] = A @ Bt^T (bf16 in/out, f32 acc). Epilogue also computes
// es[m] += sum_n C[m,n]*vsrc[n], ed[m] += sum_n C[m,n]*vdst[n] (atomic, f32 acc).
__global__ __launch_bounds__(256) void gemm_kernel(
    const unsigned short* __restrict__ A,    // [M,768] bf16
    const unsigned short* __restrict__ Bt,   // [768,768] bf16, Bt[n][k]
    unsigned short* __restrict__ C,          // [M,768] bf16
    const float* __restrict__ vsrc, const float* __restrict__ vdst,
    float* __restrict__ es, float* __restrict__ ed, int M)
{
    __shared__ __align__(16) unsigned short sA[128 * 32];   // 8 KB
    __shared__ __align__(16) unsigned short sB[128 * 32];   // 8 KB

    const int tid = threadIdx.x;
    const int lane = tid & 63, wave = tid >> 6;
    const int m0 = blockIdx.x * 128, n0 = blockIdx.y * 128;
    const int wm = wave >> 1, wn = wave & 1;
    const int l15 = lane & 15, quad = lane >> 4;

    // staging: wave w fills rows [w*32, w*32+32) of sA and sB; lane i -> +16B*i
    const int srow = lane >> 2;              // 0..15
    const int scol = (lane & 3) * 8;         // element col
    int ar0 = m0 + wave * 32 + srow;      if (ar0 >= M) ar0 = M - 1;
    int ar1 = m0 + wave * 32 + 16 + srow; if (ar1 >= M) ar1 = M - 1;
    const unsigned short* aptr0 = A + (size_t)ar0 * 768 + scol;
    const unsigned short* aptr1 = A + (size_t)ar1 * 768 + scol;
    const unsigned short* bptr0 = Bt + (size_t)(n0 + wave * 32 + srow) * 768 + scol;
    const unsigned short* bptr1 = bptr0 + (size_t)16 * 768;
    char* aldst = (char*)sA + wave * 2048;
    char* bldst = (char*)sB + wave * 2048;

    floatx4 acc[4][4];
    #pragma unroll
    for (int i = 0; i < 4; ++i)
        #pragma unroll
        for (int j = 0; j < 4; ++j)
            acc[i][j] = (floatx4){0.f, 0.f, 0.f, 0.f};

    for (int kt = 0; kt < 768; kt += 32) {
        __syncthreads();
        async_ld16(aptr0 + kt, aldst);
        async_ld16(aptr1 + kt, aldst + 1024);
        async_ld16(bptr0 + kt, bldst);
        async_ld16(bptr1 + kt, bldst + 1024);
        __syncthreads();

        bf16x8 af[4], bfr[4];
        #pragma unroll
        for (int i = 0; i < 4; ++i)
            af[i] = *(const bf16x8*)&sA[(wm * 64 + i * 16 + l15) * 32 + quad * 8];
        #pragma unroll
        for (int j = 0; j < 4; ++j)
            bfr[j] = *(const bf16x8*)&sB[(wn * 64 + j * 16 + l15) * 32 + quad * 8];
        #pragma unroll
        for (int i = 0; i < 4; ++i)
            #pragma unroll
            for (int j = 0; j < 4; ++j)
                acc[i][j] = __builtin_amdgcn_mfma_f32_16x16x32_bf16(af[i], bfr[j], acc[i][j], 0, 0, 0);
    }

    // attention-vector slice for this lane's 4 column groups
    float as_[4], ad_[4];
    #pragma unroll
    for (int j = 0; j < 4; ++j) {
        int nn = n0 + wn * 64 + j * 16 + l15;
        as_[j] = vsrc[nn]; ad_[j] = vdst[nn];
    }

    #pragma unroll
    for (int i = 0; i < 4; ++i)
        #pragma unroll
        for (int r = 0; r < 4; ++r) {
            int m = m0 + wm * 64 + i * 16 + quad * 4 + r;   // row = quad*4+reg
            float ps = 0.f, pd = 0.f;
            #pragma unroll
            for (int j = 0; j < 4; ++j) {
                float v = acc[i][j][r];
                ps += v * as_[j]; pd += v * ad_[j];
            }
            if (m < M) {
                #pragma unroll
                for (int j = 0; j < 4; ++j)
                    C[(size_t)m * 768 + n0 + wn * 64 + j * 16 + l15] = f2bf(acc[i][j][r]);
            }
            // reduce the 64-col partial dot over the 16 lanes sharing this row
            #pragma unroll
            for (int sh = 8; sh >= 1; sh >>= 1) {
                ps += __shfl_xor(ps, sh, 64);
                pd += __shfl_xor(pd, sh, 64);
            }
            if (l15 == 0 && m < M) {
                atomicAdd(&es[m], ps);
                atomicAdd(&ed[m], pd);
            }
        }
}

// -------- CSR build + es/ed zero-init ----------------------------------------
__global__ void init_kernel(int* deg, float* es1, float* ed1,
                            float* es2, float* ed2, int n) {
    int i = blockIdx.x * blockDim.x + threadIdx.x;
    if (i < n) {
        deg[i] = 1;                    // self loop pre-counted
        es1[i] = 0.f; ed1[i] = 0.f; es2[i] = 0.f; ed2[i] = 0.f;
    }
}
__global__ void count_kernel(const int* __restrict__ dst, int* __restrict__ deg, int e) {
    int i = blockIdx.x * blockDim.x + threadIdx.x;
    if (i < e) atomicAdd(&deg[dst[i]], 1);
}
__global__ __launch_bounds__(1024) void scan_kernel(
    const int* __restrict__ deg, int* __restrict__ row_ptr,
    int* __restrict__ cursor, int n)
{
    __shared__ int part[1024];
    int t = threadIdx.x;
    int per = (n + 1023) / 1024;
    int base = t * per;
    int s = 0;
    for (int i = 0; i < per; ++i) { int idx = base + i; if (idx < n) s += deg[idx]; }
    part[t] = s; __syncthreads();
    for (int off = 1; off < 1024; off <<= 1) {
        int v = (t >= off) ? part[t - off] : 0;
        __syncthreads();
        part[t] += v;
        __syncthreads();
    }
    int run = (t == 0) ? 0 : part[t - 1];
    for (int i = 0; i < per; ++i) {
        int idx = base + i;
        if (idx < n) { row_ptr[idx] = run; cursor[idx] = run; run += deg[idx]; }
    }
    if (t == 1023) row_ptr[n] = part[1023];
}
__global__ void fill_kernel(const int* __restrict__ src, const int* __restrict__ dst,
                            int* __restrict__ cursor, int* __restrict__ col_src,
                            int e, int n)
{
    int i = blockIdx.x * blockDim.x + threadIdx.x;
    if (i >= e + n) return;
    int s, d;
    if (i < e) { s = src[i]; d = dst[i]; } else { s = i - e; d = s; }
    int pos = atomicAdd(&cursor[d], 1);
    col_src[pos] = s;
}

// -------- wave-per-node segment softmax + weighted aggregation (h bf16) ------
__global__ __launch_bounds__(256) void agg_kernel(
    const unsigned short* __restrict__ h, const float* __restrict__ es,
    const float* __restrict__ ed, const int* __restrict__ row_ptr,
    const int* __restrict__ col_src, const float* __restrict__ bias,
    unsigned short* __restrict__ out_bf, float* __restrict__ out_f, int N)
{
    int wid = threadIdx.x >> 6, lane = threadIdx.x & 63;
    int n = blockIdx.x * 4 + wid;
    if (n >= N) return;
    int beg = row_ptr[n], end = row_ptr[n + 1];
    float edn = ed[n];

    // pass 1: segment max (lane-strided edges, shuffle reduce)
    float lm = -3.4e38f;
    for (int i = beg + lane; i < end; i += 64) {
        float v = es[col_src[i]] + edn;
        v = v > 0.f ? v : 0.2f * v;
        lm = fmaxf(lm, v);
    }
    #pragma unroll
    for (int m = 32; m >= 1; m >>= 1) lm = fmaxf(lm, __shfl_xor(lm, m, 64));

    // pass 2: sum of exp
    float ls = 0.f;
    for (int i = beg + lane; i < end; i += 64) {
        float v = es[col_src[i]] + edn;
        v = v > 0.f ? v : 0.2f * v;
        ls += __expf(v - lm);
    }
    #pragma unroll
    for (int m = 32; m >= 1; m >>= 1) ls += __shfl_xor(ls, m, 64);
    float rz = 1.f / ls;

    // pass 3: lane owns 12 contiguous dims; loop edges (w uniform per wave)
    float a[12];
    #pragma unroll
    for (int k = 0; k < 12; ++k) a[k] = 0.f;
    const unsigned short* hb = h + lane * 12;
    for (int i = beg; i < end; ++i) {
        int s = col_src[i];
        float u = es[s] + edn;
        u = u > 0.f ? u : 0.2f * u;
        float w = __expf(u - lm) * rz;
        const unsigned short* hr = hb + (size_t)s * 768;
        ushort4 v0 = *(const ushort4*)(hr);
        ushort4 v1 = *(const ushort4*)(hr + 4);
        ushort4 v2 = *(const ushort4*)(hr + 8);
        a[0] += w * bf2f(v0.x); a[1]  += w * bf2f(v0.y);
        a[2] += w * bf2f(v0.z); a[3]  += w * bf2f(v0.w);
        a[4] += w * bf2f(v1.x); a[5]  += w * bf2f(v1.y);
        a[6] += w * bf2f(v1.z); a[7]  += w * bf2f(v1.w);
        a[8] += w * bf2f(v2.x); a[9]  += w * bf2f(v2.y);
        a[10] += w * bf2f(v2.z); a[11] += w * bf2f(v2.w);
    }
    float4 bv0 = *(const float4*)&bias[lane * 12];
    float4 bv1 = *(const float4*)&bias[lane * 12 + 4];
    float4 bv2 = *(const float4*)&bias[lane * 12 + 8];
    float o[12];
    o[0] = a[0] + bv0.x; o[1] = a[1] + bv0.y; o[2] = a[2] + bv0.z; o[3] = a[3] + bv0.w;
    o[4] = a[4] + bv1.x; o[5] = a[5] + bv1.y; o[6] = a[6] + bv1.z; o[7] = a[7] + bv1.w;
    o[8] = a[8] + bv2.x; o[9] = a[9] + bv2.y; o[10] = a[10] + bv2.z; o[11] = a[11] + bv2.w;
    size_t base = (size_t)n * 768 + lane * 12;
    if (out_bf) {   // layer 1: relu + bf16 for next GEMM
        ushort4 w0, w1, w2;
        w0.x = f2bf(fmaxf(o[0], 0.f)); w0.y = f2bf(fmaxf(o[1], 0.f));
        w0.z = f2bf(fmaxf(o[2], 0.f)); w0.w = f2bf(fmaxf(o[3], 0.f));
        w1.x = f2bf(fmaxf(o[4], 0.f)); w1.y = f2bf(fmaxf(o[5], 0.f));
        w1.z = f2bf(fmaxf(o[6], 0.f)); w1.w = f2bf(fmaxf(o[7], 0.f));
        w2.x = f2bf(fmaxf(o[8], 0.f)); w2.y = f2bf(fmaxf(o[9], 0.f));
        w2.z = f2bf(fmaxf(o[10], 0.f)); w2.w = f2bf(fmaxf(o[11], 0.f));
        *(ushort4*)&out_bf[base] = w0;
        *(ushort4*)&out_bf[base + 4] = w1;
        *(ushort4*)&out_bf[base + 8] = w2;
    } else {        // layer 2: f32 final output
        float4 f0 = {o[0], o[1], o[2], o[3]};
        float4 f1 = {o[4], o[5], o[6], o[7]};
        float4 f2 = {o[8], o[9], o[10], o[11]};
        *(float4*)&out_f[base] = f0;
        *(float4*)&out_f[base + 4] = f1;
        *(float4*)&out_f[base + 8] = f2;
    }
}

// -----------------------------------------------------------------------------
extern "C" void kernel_launch(void* const* d_in, const int* in_sizes, int n_in,
                              void* d_out, int out_size, void* d_ws, size_t ws_size,
                              hipStream_t stream)
{
    const float* x   = (const float*)d_in[0];
    const int*   ei  = (const int*)d_in[1];
    const float* W1  = (const float*)d_in[2];
    const float* as1 = (const float*)d_in[3];
    const float* ad1 = (const float*)d_in[4];
    const float* b1  = (const float*)d_in[5];
    const float* W2  = (const float*)d_in[6];
    const float* as2 = (const float*)d_in[7];
    const float* ad2 = (const float*)d_in[8];
    const float* b2  = (const float*)d_in[9];

    const int N = in_sizes[0] / D_FEAT;
    const int E = in_sizes[1] / 2;
    const int* src = ei;
    const int* dst = ei + E;

    char* ws = (char*)d_ws;
    size_t off = 0;
    auto alloc = [&](size_t bytes) -> void* {
        void* p = ws + off;
        off += (bytes + 255) & ~(size_t)255;
        return p;
    };
    unsigned short* Wt1  = (unsigned short*)alloc((size_t)768 * 768 * 2);
    unsigned short* Wt2  = (unsigned short*)alloc((size_t)768 * 768 * 2);
    unsigned short* xb   = (unsigned short*)alloc((size_t)N * 768 * 2);
    unsigned short* h    = (unsigned short*)alloc((size_t)N * 768 * 2);   // bf16 activations
    unsigned short* x2b  = (unsigned short*)alloc((size_t)N * 768 * 2);
    float*          es1  = (float*)alloc((size_t)N * 4);
    float*          ed1  = (float*)alloc((size_t)N * 4);
    float*          es2  = (float*)alloc((size_t)N * 4);
    float*          ed2  = (float*)alloc((size_t)N * 4);
    int*            deg  = (int*)alloc((size_t)N * 4);
    int*            cur  = (int*)alloc((size_t)N * 4);
    int*            rowp = (int*)alloc((size_t)(N + 1) * 4);
    int*            col  = (int*)alloc((size_t)(E + N) * 4);

    // prep: x -> bf16, W -> bf16 transposed, CSR by dst, zero es/ed
    int n4 = N * 768 / 4;
    conv_kernel<<<(n4 + 255) / 256, 256, 0, stream>>>(x, xb, n4);
    dim3 tgrid(D_FEAT / 32, D_FEAT / 32);
    transpose_kernel<<<tgrid, 256, 0, stream>>>(W1, Wt1);
    transpose_kernel<<<tgrid, 256, 0, stream>>>(W2, Wt2);
    init_kernel<<<(N + 255) / 256, 256, 0, stream>>>(deg, es1, ed1, es2, ed2, N);
    count_kernel<<<(E + 255) / 256, 256, 0, stream>>>(dst, deg, E);
    scan_kernel<<<1, 1024, 0, stream>>>(deg, rowp, cur, N);
    fill_kernel<<<(E + N + 255) / 256, 256, 0, stream>>>(src, dst, cur, col, E, N);

    dim3 ggrid((N + 127) / 128, D_FEAT / 128);
    // layer 1
    gemm_kernel<<<ggrid, 256, 0, stream>>>(xb, Wt1, h, as1, ad1, es1, ed1, N);
    agg_kernel<<<(N + 3) / 4, 256, 0, stream>>>(h, es1, ed1, rowp, col, b1, x2b, nullptr, N);
    // layer 2
    gemm_kernel<<<ggrid, 256, 0, stream>>>(x2b, Wt2, h, as2, ad2, es2, ed2, N);
    agg_kernel<<<(N + 3) / 4, 256, 0, stream>>>(h, es2, ed2, rowp, col, b2, nullptr, (float*)d_out, N);
}

// Round 5
// 238.120 us; speedup vs baseline: 1.3335x; 1.0596x over previous
//
#include <hip/hip_runtime.h>
#include <hip/hip_bf16.h>

#define D_FEAT 768

typedef __bf16 bf16x8 __attribute__((ext_vector_type(8)));
typedef float floatx4 __attribute__((ext_vector_type(4)));

__device__ __forceinline__ float bf2f(unsigned short u) {
    unsigned int x = ((unsigned int)u) << 16;
    return __builtin_bit_cast(float, x);
}
__device__ __forceinline__ unsigned short f2bf(float f) {
    unsigned int x = __builtin_bit_cast(unsigned int, f);
    unsigned int lsb = (x >> 16) & 1u;
    x += 0x7fffu + lsb;            // round-to-nearest-even
    return (unsigned short)(x >> 16);
}
__device__ __forceinline__ void async_ld16(const void* g, void* l) {
    __builtin_amdgcn_global_load_lds(
        (__attribute__((address_space(1))) void*)(g),
        (__attribute__((address_space(3))) void*)(l), 16, 0, 0);
}

// -------- x f32 -> bf16 pre-convert + deg/es/ed init -------------------------
__global__ __launch_bounds__(256) void conv_init_kernel(
    const float* __restrict__ x, unsigned short* __restrict__ xb, int n4,
    int* __restrict__ deg, float* __restrict__ es1, float* __restrict__ ed1,
    float* __restrict__ es2, float* __restrict__ ed2, int N)
{
    int i = blockIdx.x * 256 + threadIdx.x;
    if (i < n4) {
        float4 v = ((const float4*)x)[i];
        ushort4 o;
        o.x = f2bf(v.x); o.y = f2bf(v.y); o.z = f2bf(v.z); o.w = f2bf(v.w);
        ((ushort4*)xb)[i] = o;
    }
    if (i < N) {
        deg[i] = 1;                    // self loop pre-counted
        es1[i] = 0.f; ed1[i] = 0.f; es2[i] = 0.f; ed2[i] = 0.f;
    }
}

// -------- W convert+transpose (both layers via blockIdx.z) -------------------
__global__ __launch_bounds__(256) void transpose_kernel(
    const float* __restrict__ W1, const float* __restrict__ W2,
    unsigned short* __restrict__ Wt1, unsigned short* __restrict__ Wt2)
{
    const float* W = blockIdx.z ? W2 : W1;
    unsigned short* Wt = blockIdx.z ? Wt2 : Wt1;
    __shared__ float tile[32][33];
    int x0 = blockIdx.x * 32, y0 = blockIdx.y * 32;
    int tx = threadIdx.x & 31, ty = threadIdx.x >> 5;   // 32 x 8
    for (int r = ty; r < 32; r += 8)
        tile[r][tx] = W[(size_t)(y0 + r) * D_FEAT + x0 + tx];
    __syncthreads();
    for (int r = ty; r < 32; r += 8)
        Wt[(size_t)(x0 + r) * D_FEAT + y0 + tx] = f2bf(tile[tx][r]);
}

// -------- GEMM 128x128 + fused attention dots --------------------------------
// C[M,768] = A @ Bt^T (bf16 in/out, f32 acc). Epilogue also computes
// es[m] += sum_n C[m,n]*vsrc[n], ed[m] += sum_n C[m,n]*vdst[n] (atomic, f32 acc).
__global__ __launch_bounds__(256) void gemm_kernel(
    const unsigned short* __restrict__ A,    // [M,768] bf16
    const unsigned short* __restrict__ Bt,   // [768,768] bf16, Bt[n][k]
    unsigned short* __restrict__ C,          // [M,768] bf16
    const float* __restrict__ vsrc, const float* __restrict__ vdst,
    float* __restrict__ es, float* __restrict__ ed, int M)
{
    __shared__ __align__(16) unsigned short sA[128 * 32];   // 8 KB
    __shared__ __align__(16) unsigned short sB[128 * 32];   // 8 KB

    const int tid = threadIdx.x;
    const int lane = tid & 63, wave = tid >> 6;
    const int m0 = blockIdx.x * 128, n0 = blockIdx.y * 128;
    const int wm = wave >> 1, wn = wave & 1;
    const int l15 = lane & 15, quad = lane >> 4;

    // staging: wave w fills rows [w*32, w*32+32) of sA and sB; lane i -> +16B*i
    const int srow = lane >> 2;              // 0..15
    const int scol = (lane & 3) * 8;         // element col
    int ar0 = m0 + wave * 32 + srow;      if (ar0 >= M) ar0 = M - 1;
    int ar1 = m0 + wave * 32 + 16 + srow; if (ar1 >= M) ar1 = M - 1;
    const unsigned short* aptr0 = A + (size_t)ar0 * 768 + scol;
    const unsigned short* aptr1 = A + (size_t)ar1 * 768 + scol;
    const unsigned short* bptr0 = Bt + (size_t)(n0 + wave * 32 + srow) * 768 + scol;
    const unsigned short* bptr1 = bptr0 + (size_t)16 * 768;
    char* aldst = (char*)sA + wave * 2048;
    char* bldst = (char*)sB + wave * 2048;

    floatx4 acc[4][4];
    #pragma unroll
    for (int i = 0; i < 4; ++i)
        #pragma unroll
        for (int j = 0; j < 4; ++j)
            acc[i][j] = (floatx4){0.f, 0.f, 0.f, 0.f};

    for (int kt = 0; kt < 768; kt += 32) {
        __syncthreads();
        async_ld16(aptr0 + kt, aldst);
        async_ld16(aptr1 + kt, aldst + 1024);
        async_ld16(bptr0 + kt, bldst);
        async_ld16(bptr1 + kt, bldst + 1024);
        __syncthreads();

        bf16x8 af[4], bfr[4];
        #pragma unroll
        for (int i = 0; i < 4; ++i)
            af[i] = *(const bf16x8*)&sA[(wm * 64 + i * 16 + l15) * 32 + quad * 8];
        #pragma unroll
        for (int j = 0; j < 4; ++j)
            bfr[j] = *(const bf16x8*)&sB[(wn * 64 + j * 16 + l15) * 32 + quad * 8];
        #pragma unroll
        for (int i = 0; i < 4; ++i)
            #pragma unroll
            for (int j = 0; j < 4; ++j)
                acc[i][j] = __builtin_amdgcn_mfma_f32_16x16x32_bf16(af[i], bfr[j], acc[i][j], 0, 0, 0);
    }

    // attention-vector slice for this lane's 4 column groups
    float as_[4], ad_[4];
    #pragma unroll
    for (int j = 0; j < 4; ++j) {
        int nn = n0 + wn * 64 + j * 16 + l15;
        as_[j] = vsrc[nn]; ad_[j] = vdst[nn];
    }

    #pragma unroll
    for (int i = 0; i < 4; ++i)
        #pragma unroll
        for (int r = 0; r < 4; ++r) {
            int m = m0 + wm * 64 + i * 16 + quad * 4 + r;   // row = quad*4+reg
            float ps = 0.f, pd = 0.f;
            #pragma unroll
            for (int j = 0; j < 4; ++j) {
                float v = acc[i][j][r];
                ps += v * as_[j]; pd += v * ad_[j];
            }
            if (m < M) {
                #pragma unroll
                for (int j = 0; j < 4; ++j)
                    C[(size_t)m * 768 + n0 + wn * 64 + j * 16 + l15] = f2bf(acc[i][j][r]);
            }
            // reduce the 64-col partial dot over the 16 lanes sharing this row
            #pragma unroll
            for (int sh = 8; sh >= 1; sh >>= 1) {
                ps += __shfl_xor(ps, sh, 64);
                pd += __shfl_xor(pd, sh, 64);
            }
            if (l15 == 0 && m < M) {
                atomicAdd(&es[m], ps);
                atomicAdd(&ed[m], pd);
            }
        }
}

// -------- CSR build ----------------------------------------------------------
__global__ void count_kernel(const int* __restrict__ dst, int* __restrict__ deg, int e) {
    int i = blockIdx.x * blockDim.x + threadIdx.x;
    if (i < e) atomicAdd(&deg[dst[i]], 1);
}
__global__ __launch_bounds__(1024) void scan_kernel(
    const int* __restrict__ deg, int* __restrict__ row_ptr,
    int* __restrict__ cursor, int n)
{
    __shared__ int part[1024];
    int t = threadIdx.x;
    int per = (n + 1023) / 1024;
    int base = t * per;
    int s = 0;
    for (int i = 0; i < per; ++i) { int idx = base + i; if (idx < n) s += deg[idx]; }
    part[t] = s; __syncthreads();
    for (int off = 1; off < 1024; off <<= 1) {
        int v = (t >= off) ? part[t - off] : 0;
        __syncthreads();
        part[t] += v;
        __syncthreads();
    }
    int run = (t == 0) ? 0 : part[t - 1];
    for (int i = 0; i < per; ++i) {
        int idx = base + i;
        if (idx < n) { row_ptr[idx] = run; cursor[idx] = run; run += deg[idx]; }
    }
    if (t == 1023) row_ptr[n] = part[1023];
}
__global__ void fill_kernel(const int* __restrict__ src, const int* __restrict__ dst,
                            int* __restrict__ cursor, int* __restrict__ col_src,
                            int e, int n)
{
    int i = blockIdx.x * blockDim.x + threadIdx.x;
    if (i >= e + n) return;
    int s, d;
    if (i < e) { s = src[i]; d = dst[i]; } else { s = i - e; d = s; }
    int pos = atomicAdd(&cursor[d], 1);
    col_src[pos] = s;
}

// -------- wave-per-node segment softmax + weighted aggregation (h bf16) ------
// Fast path (deg<=64): edge (src, weight) held in registers, one edge per lane;
// gather loop gets them via shuffle -> only independent h-row loads touch memory.
__global__ __launch_bounds__(256) void agg_kernel(
    const unsigned short* __restrict__ h, const float* __restrict__ es,
    const float* __restrict__ ed, const int* __restrict__ row_ptr,
    const int* __restrict__ col_src, const float* __restrict__ bias,
    unsigned short* __restrict__ out_bf, float* __restrict__ out_f, int N)
{
    int wid = threadIdx.x >> 6, lane = threadIdx.x & 63;
    int n = blockIdx.x * 4 + wid;
    if (n >= N) return;
    int beg = row_ptr[n], end = row_ptr[n + 1], deg = end - beg;
    float edn = ed[n];

    float a[12];
    #pragma unroll
    for (int k = 0; k < 12; ++k) a[k] = 0.f;
    const unsigned short* hb = h + lane * 12;

    if (deg <= 64) {
        int s = 0; float v = -3.4e38f;
        if (lane < deg) {
            s = col_src[beg + lane];
            v = es[s] + edn;
            v = v > 0.f ? v : 0.2f * v;
        }
        float lm = v;
        #pragma unroll
        for (int m = 32; m >= 1; m >>= 1) lm = fmaxf(lm, __shfl_xor(lm, m, 64));
        float w = (lane < deg) ? __expf(v - lm) : 0.f;
        float ls = w;
        #pragma unroll
        for (int m = 32; m >= 1; m >>= 1) ls += __shfl_xor(ls, m, 64);
        w *= (1.f / ls);

        int i = 0;
        for (; i + 2 <= deg; i += 2) {
            int   s0 = __shfl(s, i, 64),     s1 = __shfl(s, i + 1, 64);
            float w0 = __shfl(w, i, 64),     w1 = __shfl(w, i + 1, 64);
            const unsigned short* h0 = hb + (size_t)s0 * 768;
            const unsigned short* h1 = hb + (size_t)s1 * 768;
            ushort4 p0 = *(const ushort4*)(h0);
            ushort4 p1 = *(const ushort4*)(h0 + 4);
            ushort4 p2 = *(const ushort4*)(h0 + 8);
            ushort4 q0 = *(const ushort4*)(h1);
            ushort4 q1 = *(const ushort4*)(h1 + 4);
            ushort4 q2 = *(const ushort4*)(h1 + 8);
            a[0]  += w0 * bf2f(p0.x) + w1 * bf2f(q0.x);
            a[1]  += w0 * bf2f(p0.y) + w1 * bf2f(q0.y);
            a[2]  += w0 * bf2f(p0.z) + w1 * bf2f(q0.z);
            a[3]  += w0 * bf2f(p0.w) + w1 * bf2f(q0.w);
            a[4]  += w0 * bf2f(p1.x) + w1 * bf2f(q1.x);
            a[5]  += w0 * bf2f(p1.y) + w1 * bf2f(q1.y);
            a[6]  += w0 * bf2f(p1.z) + w1 * bf2f(q1.z);
            a[7]  += w0 * bf2f(p1.w) + w1 * bf2f(q1.w);
            a[8]  += w0 * bf2f(p2.x) + w1 * bf2f(q2.x);
            a[9]  += w0 * bf2f(p2.y) + w1 * bf2f(q2.y);
            a[10] += w0 * bf2f(p2.z) + w1 * bf2f(q2.z);
            a[11] += w0 * bf2f(p2.w) + w1 * bf2f(q2.w);
        }
        if (i < deg) {
            int   s0 = __shfl(s, i, 64);
            float w0 = __shfl(w, i, 64);
            const unsigned short* h0 = hb + (size_t)s0 * 768;
            ushort4 p0 = *(const ushort4*)(h0);
            ushort4 p1 = *(const ushort4*)(h0 + 4);
            ushort4 p2 = *(const ushort4*)(h0 + 8);
            a[0]  += w0 * bf2f(p0.x); a[1]  += w0 * bf2f(p0.y);
            a[2]  += w0 * bf2f(p0.z); a[3]  += w0 * bf2f(p0.w);
            a[4]  += w0 * bf2f(p1.x); a[5]  += w0 * bf2f(p1.y);
            a[6]  += w0 * bf2f(p1.z); a[7]  += w0 * bf2f(p1.w);
            a[8]  += w0 * bf2f(p2.x); a[9]  += w0 * bf2f(p2.y);
            a[10] += w0 * bf2f(p2.z); a[11] += w0 * bf2f(p2.w);
        }
    } else {
        // slow path: streaming recompute (correct for any degree)
        float lm = -3.4e38f;
        for (int i = beg + lane; i < end; i += 64) {
            float v = es[col_src[i]] + edn;
            v = v > 0.f ? v : 0.2f * v;
            lm = fmaxf(lm, v);
        }
        #pragma unroll
        for (int m = 32; m >= 1; m >>= 1) lm = fmaxf(lm, __shfl_xor(lm, m, 64));
        float ls = 0.f;
        for (int i = beg + lane; i < end; i += 64) {
            float v = es[col_src[i]] + edn;
            v = v > 0.f ? v : 0.2f * v;
            ls += __expf(v - lm);
        }
        #pragma unroll
        for (int m = 32; m >= 1; m >>= 1) ls += __shfl_xor(ls, m, 64);
        float rz = 1.f / ls;
        for (int i = beg; i < end; ++i) {
            int sidx = col_src[i];
            float u = es[sidx] + edn;
            u = u > 0.f ? u : 0.2f * u;
            float w = __expf(u - lm) * rz;
            const unsigned short* hr = hb + (size_t)sidx * 768;
            ushort4 v0 = *(const ushort4*)(hr);
            ushort4 v1 = *(const ushort4*)(hr + 4);
            ushort4 v2 = *(const ushort4*)(hr + 8);
            a[0]  += w * bf2f(v0.x); a[1]  += w * bf2f(v0.y);
            a[2]  += w * bf2f(v0.z); a[3]  += w * bf2f(v0.w);
            a[4]  += w * bf2f(v1.x); a[5]  += w * bf2f(v1.y);
            a[6]  += w * bf2f(v1.z); a[7]  += w * bf2f(v1.w);
            a[8]  += w * bf2f(v2.x); a[9]  += w * bf2f(v2.y);
            a[10] += w * bf2f(v2.z); a[11] += w * bf2f(v2.w);
        }
    }

    float4 bv0 = *(const float4*)&bias[lane * 12];
    float4 bv1 = *(const float4*)&bias[lane * 12 + 4];
    float4 bv2 = *(const float4*)&bias[lane * 12 + 8];
    float o[12];
    o[0] = a[0] + bv0.x; o[1] = a[1] + bv0.y; o[2] = a[2] + bv0.z; o[3] = a[3] + bv0.w;
    o[4] = a[4] + bv1.x; o[5] = a[5] + bv1.y; o[6] = a[6] + bv1.z; o[7] = a[7] + bv1.w;
    o[8] = a[8] + bv2.x; o[9] = a[9] + bv2.y; o[10] = a[10] + bv2.z; o[11] = a[11] + bv2.w;
    size_t base = (size_t)n * 768 + lane * 12;
    if (out_bf) {   // layer 1: relu + bf16 for next GEMM
        ushort4 w0, w1, w2;
        w0.x = f2bf(fmaxf(o[0], 0.f)); w0.y = f2bf(fmaxf(o[1], 0.f));
        w0.z = f2bf(fmaxf(o[2], 0.f)); w0.w = f2bf(fmaxf(o[3], 0.f));
        w1.x = f2bf(fmaxf(o[4], 0.f)); w1.y = f2bf(fmaxf(o[5], 0.f));
        w1.z = f2bf(fmaxf(o[6], 0.f)); w1.w = f2bf(fmaxf(o[7], 0.f));
        w2.x = f2bf(fmaxf(o[8], 0.f)); w2.y = f2bf(fmaxf(o[9], 0.f));
        w2.z = f2bf(fmaxf(o[10], 0.f)); w2.w = f2bf(fmaxf(o[11], 0.f));
        *(ushort4*)&out_bf[base] = w0;
        *(ushort4*)&out_bf[base + 4] = w1;
        *(ushort4*)&out_bf[base + 8] = w2;
    } else {        // layer 2: f32 final output
        float4 f0 = {o[0], o[1], o[2], o[3]};
        float4 f1 = {o[4], o[5], o[6], o[7]};
        float4 f2 = {o[8], o[9], o[10], o[11]};
        *(float4*)&out_f[base] = f0;
        *(float4*)&out_f[base + 4] = f1;
        *(float4*)&out_f[base + 8] = f2;
    }
}

// -----------------------------------------------------------------------------
extern "C" void kernel_launch(void* const* d_in, const int* in_sizes, int n_in,
                              void* d_out, int out_size, void* d_ws, size_t ws_size,
                              hipStream_t stream)
{
    const float* x   = (const float*)d_in[0];
    const int*   ei  = (const int*)d_in[1];
    const float* W1  = (const float*)d_in[2];
    const float* as1 = (const float*)d_in[3];
    const float* ad1 = (const float*)d_in[4];
    const float* b1  = (const float*)d_in[5];
    const float* W2  = (const float*)d_in[6];
    const float* as2 = (const float*)d_in[7];
    const float* ad2 = (const float*)d_in[8];
    const float* b2  = (const float*)d_in[9];

    const int N = in_sizes[0] / D_FEAT;
    const int E = in_sizes[1] / 2;
    const int* src = ei;
    const int* dst = ei + E;

    char* ws = (char*)d_ws;
    size_t off = 0;
    auto alloc = [&](size_t bytes) -> void* {
        void* p = ws + off;
        off += (bytes + 255) & ~(size_t)255;
        return p;
    };
    unsigned short* Wt1  = (unsigned short*)alloc((size_t)768 * 768 * 2);
    unsigned short* Wt2  = (unsigned short*)alloc((size_t)768 * 768 * 2);
    unsigned short* xb   = (unsigned short*)alloc((size_t)N * 768 * 2);
    unsigned short* h    = (unsigned short*)alloc((size_t)N * 768 * 2);   // bf16 activations
    unsigned short* x2b  = (unsigned short*)alloc((size_t)N * 768 * 2);
    float*          es1  = (float*)alloc((size_t)N * 4);
    float*          ed1  = (float*)alloc((size_t)N * 4);
    float*          es2  = (float*)alloc((size_t)N * 4);
    float*          ed2  = (float*)alloc((size_t)N * 4);
    int*            deg  = (int*)alloc((size_t)N * 4);
    int*            cur  = (int*)alloc((size_t)N * 4);
    int*            rowp = (int*)alloc((size_t)(N + 1) * 4);
    int*            col  = (int*)alloc((size_t)(E + N) * 4);

    // prep: x -> bf16 (+ deg/es/ed init), W -> bf16 transposed, CSR by dst
    int n4 = N * 768 / 4;
    conv_init_kernel<<<(n4 + 255) / 256, 256, 0, stream>>>(x, xb, n4, deg, es1, ed1, es2, ed2, N);
    dim3 tgrid(D_FEAT / 32, D_FEAT / 32, 2);
    transpose_kernel<<<tgrid, 256, 0, stream>>>(W1, W2, Wt1, Wt2);
    count_kernel<<<(E + 255) / 256, 256, 0, stream>>>(dst, deg, E);
    scan_kernel<<<1, 1024, 0, stream>>>(deg, rowp, cur, N);
    fill_kernel<<<(E + N + 255) / 256, 256, 0, stream>>>(src, dst, cur, col, E, N);

    dim3 ggrid((N + 127) / 128, D_FEAT / 128);
    // layer 1
    gemm_kernel<<<ggrid, 256, 0, stream>>>(xb, Wt1, h, as1, ad1, es1, ed1, N);
    agg_kernel<<<(N + 3) / 4, 256, 0, stream>>>(h, es1, ed1, rowp, col, b1, x2b, nullptr, N);
    // layer 2
    gemm_kernel<<<ggrid, 256, 0, stream>>>(x2b, Wt2, h, as2, ad2, es2, ed2, N);
    agg_kernel<<<(N + 3) / 4, 256, 0, stream>>>(h, es2, ed2, rowp, col, b2, nullptr, (float*)d_out, N);
}